// Round 10
// baseline (917.062 us; speedup 1.0000x reference)
//
#include <hip/hip_runtime.h>

#define N_NODES 8000
#define FEAT 64
#define HID 128
#define LOOKBACK 12
#define CAP 64
#define NBLK 500

// ---------------- zero counters + barrier words ----------------
__global__ __launch_bounds__(256)
void zero_kernel(int* __restrict__ cnt, unsigned* __restrict__ bar) {
    int g = blockIdx.x * 256 + threadIdx.x;
    if (g < N_NODES) cnt[g] = 0;
    if (g < 32) bar[g] = 0u;
}

// ---------------- adjacency pattern extraction (atomic) ----------------
__global__ __launch_bounds__(256)
void build_adj_kernel(const float* __restrict__ adj, int* __restrict__ cnt,
                      int* __restrict__ lists) {
    long q = (long)blockIdx.x * 256 + threadIdx.x;           // float4 index
    const long NQ = (long)N_NODES * N_NODES / 4;
    if (q >= NQ) return;
    int i  = (int)(q / (N_NODES / 4));
    int j0 = (int)(q % (N_NODES / 4)) * 4;
    float4 w = *reinterpret_cast<const float4*>(adj + (long)i * N_NODES + j0);
    float wv[4] = {w.x, w.y, w.z, w.w};
    #pragma unroll
    for (int c = 0; c < 4; ++c) {
        if (wv[c] != 0.0f) {
            int j = j0 + c;
            int p = atomicAdd(&cnt[j], 1);
            if (p < CAP) lists[(long)j * CAP + p] = i;       // edge i -> j
        }
    }
}

// ---------------- software grid barrier (500 co-resident blocks) ----------------
// bar[0] = arrival count, bar[16] = generation (separate cache lines).
__device__ __forceinline__ void gsync(unsigned* __restrict__ bar) {
    __syncthreads();
    if (threadIdx.x == 0) {
        __threadfence();    // release: drain stores, wb L2 (agent scope)
        unsigned g = __hip_atomic_load(&bar[16], __ATOMIC_RELAXED, __HIP_MEMORY_SCOPE_AGENT);
        unsigned a = __hip_atomic_fetch_add(&bar[0], 1u, __ATOMIC_ACQ_REL, __HIP_MEMORY_SCOPE_AGENT);
        if (a == (unsigned)(NBLK - 1)) {
            __hip_atomic_store(&bar[0], 0u, __ATOMIC_RELAXED, __HIP_MEMORY_SCOPE_AGENT);
            __hip_atomic_fetch_add(&bar[16], 1u, __ATOMIC_RELEASE, __HIP_MEMORY_SCOPE_AGENT);
        } else {
            long it = 0;
            while (__hip_atomic_load(&bar[16], __ATOMIC_ACQUIRE, __HIP_MEMORY_SCOPE_AGENT) == g) {
                if (++it > (1L << 23)) break;   // anti-hang bail (~0.7s; never in practice)
            }
        }
    }
    __syncthreads();
    __threadfence();        // acquire: invalidate stale L1/L2 for all threads
}

// ---------------- persistent mega-kernel: prep + init + 3 Euler steps ----------------
// 500 blocks x 256 threads, 2 blocks/CU (61 KB LDS) -> all blocks co-resident.
// Phase bodies copied verbatim from the round-7 kernels -> bit-identical output.
__global__ __launch_bounds__(256, 2)
void mega_kernel(const float* __restrict__ tspan, const float* __restrict__ x,
                 const float* __restrict__ We1, const float* __restrict__ be1,
                 const float* __restrict__ We2, const float* __restrict__ be2,
                 const float* __restrict__ Wf1, const float* __restrict__ bf1,
                 const float* __restrict__ Wf2, const float* __restrict__ bf2,
                 const float* __restrict__ Wl1, const float* __restrict__ bl1,
                 const float* __restrict__ Wr1,
                 const float* __restrict__ Wl2, const float* __restrict__ bl2,
                 const float* __restrict__ Wr2,
                 int* __restrict__ cnt, int* __restrict__ lists,
                 float* __restrict__ degf,
                 float* __restrict__ Ws1, float* __restrict__ Wc2,
                 float* __restrict__ pl, float* __restrict__ q,
                 float* __restrict__ out, unsigned* __restrict__ bar) {
    __shared__ float v[16][132];     // [node][k]: k<64 aggr, k>=64 h row
    __shared__ float rr[16][132];
    __shared__ float tt[16][132];
    __shared__ float xsl[16][68];
    __shared__ float wbuf[64 * 128]; // 32 KB weight panel / init tables
    const int tid = threadIdx.x;
    const int bid = blockIdx.x;

    // ======== phase A: sort lists + deg + weight stacking + init encoder ========
    {
        const int wv = tid >> 6, lane = tid & 63;
        #pragma unroll 1
        for (int r = 0; r < 4; ++r) {
            const int n = (bid * 4 + wv) + 2000 * r;
            int m = cnt[n]; if (m > CAP) m = CAP;
            int val = (lane < m) ? lists[(long)n * CAP + lane] : 0x7FFFFFFF;
            #pragma unroll
            for (int k = 2; k <= 64; k <<= 1) {
                #pragma unroll
                for (int j = k >> 1; j > 0; j >>= 1) {
                    int other = __shfl_xor(val, j);
                    bool keepMin = (((lane & j) == 0) == ((lane & k) == 0));
                    int mn = val < other ? val : other;
                    int mx = val < other ? other : val;
                    val = keepMin ? mn : mx;
                }
            }
            lists[(long)n * CAP + lane] = val;
            if (lane == 0) { cnt[n] = m; degf[n] = (float)(m > 0 ? m : 1); }
        }
        const int gid = bid * 256 + tid;        // 128000 threads
        for (int u = gid; u < 2 * 128 * 128; u += 128000) {
            if (u < 128 * 128) {                // Ws1[k][j] = [Wl1;Wr1] row-stacked
                int k = u >> 7, j = u & 127;
                Ws1[u] = (k < 64) ? Wl1[k * 128 + j] : Wr1[(k - 64) * 128 + j];
            } else {                            // Wc2[k][j] = [Wl2 | Wr2] col-stacked
                int w = u - 128 * 128;
                int k = w >> 7, j = w & 127;
                Wc2[w] = (j < 64) ? Wl2[k * 64 + j] : Wr2[k * 64 + (j - 64)];
            }
        }
        // ---- init encoder (tables in wbuf) ----
        float* sW1T = wbuf;              // [h][l], 1536
        float* sB1  = wbuf + 1536;       // 128
        float* sW2  = wbuf + 1664;       // 128
        __syncthreads();
        for (int e = tid; e < HID * LOOKBACK; e += 256) {
            int l = e / HID, hh = e % HID;
            sW1T[hh * LOOKBACK + l] = We1[e];
        }
        for (int e = tid; e < HID; e += 256) { sB1[e] = be1[e]; sW2[e] = We2[e]; }
        __syncthreads();
        int g = (bid * 256 + tid) * 4;          // 500*256*4 == N*F exactly
        float xv[4][LOOKBACK];
        #pragma unroll
        for (int l = 0; l < LOOKBACK; ++l) {
            float4 vv = *reinterpret_cast<const float4*>(x + (long)l * N_NODES * FEAT + g);
            xv[0][l] = vv.x; xv[1][l] = vv.y; xv[2][l] = vv.z; xv[3][l] = vv.w;
        }
        float b2 = be2[0];
        float acc[4] = {b2, b2, b2, b2};
        for (int hh = 0; hh < HID; ++hh) {
            float s0 = sB1[hh], s1 = s0, s2 = s0, s3 = s0;
            #pragma unroll
            for (int l = 0; l < LOOKBACK; ++l) {
                float w = sW1T[hh * LOOKBACK + l];
                s0 += xv[0][l] * w; s1 += xv[1][l] * w;
                s2 += xv[2][l] * w; s3 += xv[3][l] * w;
            }
            float w2 = sW2[hh];
            acc[0] += fmaxf(s0, 0.0f) * w2; acc[1] += fmaxf(s1, 0.0f) * w2;
            acc[2] += fmaxf(s2, 0.0f) * w2; acc[3] += fmaxf(s3, 0.0f) * w2;
        }
        float4 o = {acc[0], acc[1], acc[2], acc[3]};
        *reinterpret_cast<float4*>(out + g) = o;
    }
    gsync(bar);

    // ======== 3 Euler steps ========
    const int ln = tid >> 4, jg = tid & 15;
    const int nb = bid * 16;
    const int n  = nb + ln;
    const int c0 = jg * 4;
    for (int s = 0; s < 3; ++s) {
        const float* h     = out + (long)s * N_NODES * FEAT;
        float*       hnext = out + (long)(s + 1) * N_NODES * FEAT;
        // ===== sageproj phase (R7 body) =====
        {   // gather: 16 threads/node, 4 feats each
            const int m = cnt[n];
            const int* l = lists + (long)n * CAP;
            const float inv = 1.0f / degf[n];
            float4 a = {0, 0, 0, 0};
            for (int e = 0; e < m; ++e) {
                float4 b = *reinterpret_cast<const float4*>(h + (long)l[e] * FEAT + c0);
                a.x += b.x; a.y += b.y; a.z += b.z; a.w += b.w;
            }
            float4 av = {a.x * inv, a.y * inv, a.z * inv, a.w * inv};
            *reinterpret_cast<float4*>(&v[ln][c0]) = av;
            *reinterpret_cast<float4*>(&v[ln][64 + c0]) =
                *reinterpret_cast<const float4*>(h + (long)n * FEAT + c0);
        }
        // P1: rr = relu([aggr|h] @ Ws1 + bl1), K=128 in 2 chunks
        {
            float4 b0 = *reinterpret_cast<const float4*>(bl1 + c0);
            float4 b1 = *reinterpret_cast<const float4*>(bl1 + 64 + c0);
            float A0[4] = {b0.x, b0.y, b0.z, b0.w};
            float A1[4] = {b1.x, b1.y, b1.z, b1.w};
            for (int kc = 0; kc < 2; ++kc) {
                __syncthreads();
                for (int e = tid; e < 2048; e += 256)
                    *(reinterpret_cast<float4*>(wbuf) + e) =
                        *(reinterpret_cast<const float4*>(Ws1 + kc * 8192) + e);
                __syncthreads();
                #pragma unroll 4
                for (int k = 0; k < 64; ++k) {
                    float a = v[ln][kc * 64 + k];
                    float4 w0 = *reinterpret_cast<const float4*>(&wbuf[k * 128 + c0]);
                    float4 w1 = *reinterpret_cast<const float4*>(&wbuf[k * 128 + 64 + c0]);
                    A0[0] += a * w0.x; A0[1] += a * w0.y; A0[2] += a * w0.z; A0[3] += a * w0.w;
                    A1[0] += a * w1.x; A1[1] += a * w1.y; A1[2] += a * w1.z; A1[3] += a * w1.w;
                }
            }
            float4 o0 = {fmaxf(A0[0],0.f), fmaxf(A0[1],0.f), fmaxf(A0[2],0.f), fmaxf(A0[3],0.f)};
            float4 o1 = {fmaxf(A1[0],0.f), fmaxf(A1[1],0.f), fmaxf(A1[2],0.f), fmaxf(A1[3],0.f)};
            *reinterpret_cast<float4*>(&rr[ln][c0]) = o0;
            *reinterpret_cast<float4*>(&rr[ln][64 + c0]) = o1;
        }
        // P2: tt = relu(h @ Wf1 + bf1), K=64
        {
            float4 b0 = *reinterpret_cast<const float4*>(bf1 + c0);
            float4 b1 = *reinterpret_cast<const float4*>(bf1 + 64 + c0);
            float A0[4] = {b0.x, b0.y, b0.z, b0.w};
            float A1[4] = {b1.x, b1.y, b1.z, b1.w};
            __syncthreads();
            for (int e = tid; e < 2048; e += 256)
                *(reinterpret_cast<float4*>(wbuf) + e) =
                    *(reinterpret_cast<const float4*>(Wf1) + e);
            __syncthreads();
            #pragma unroll 4
            for (int k = 0; k < 64; ++k) {
                float a = v[ln][64 + k];
                float4 w0 = *reinterpret_cast<const float4*>(&wbuf[k * 128 + c0]);
                float4 w1 = *reinterpret_cast<const float4*>(&wbuf[k * 128 + 64 + c0]);
                A0[0] += a * w0.x; A0[1] += a * w0.y; A0[2] += a * w0.z; A0[3] += a * w0.w;
                A1[0] += a * w1.x; A1[1] += a * w1.y; A1[2] += a * w1.z; A1[3] += a * w1.w;
            }
            float4 o0 = {fmaxf(A0[0],0.f), fmaxf(A0[1],0.f), fmaxf(A0[2],0.f), fmaxf(A0[3],0.f)};
            float4 o1 = {fmaxf(A1[0],0.f), fmaxf(A1[1],0.f), fmaxf(A1[2],0.f), fmaxf(A1[3],0.f)};
            *reinterpret_cast<float4*>(&tt[ln][c0]) = o0;
            *reinterpret_cast<float4*>(&tt[ln][64 + c0]) = o1;
        }
        // P3: xsl = tt @ Wf2 + bf2 (Wf2 = [128][64])
        {
            float4 b0 = *reinterpret_cast<const float4*>(bf2 + c0);
            float X[4] = {b0.x, b0.y, b0.z, b0.w};
            __syncthreads();
            for (int e = tid; e < 2048; e += 256)
                *(reinterpret_cast<float4*>(wbuf) + e) =
                    *(reinterpret_cast<const float4*>(Wf2) + e);
            __syncthreads();
            #pragma unroll 4
            for (int k = 0; k < 128; ++k) {
                float a = tt[ln][k];
                float4 w = *reinterpret_cast<const float4*>(&wbuf[k * 64 + c0]);
                X[0] += a * w.x; X[1] += a * w.y; X[2] += a * w.z; X[3] += a * w.w;
            }
            float4 o = {X[0], X[1], X[2], X[3]};
            *reinterpret_cast<float4*>(&xsl[ln][c0]) = o;
        }
        // P4: [pl|q] = rr @ Wc2 (+ bl2 + xsl on q half), K=128 in 2 chunks
        {
            float P0[4] = {0, 0, 0, 0};
            float P1[4] = {0, 0, 0, 0};
            for (int kc = 0; kc < 2; ++kc) {
                __syncthreads();
                for (int e = tid; e < 2048; e += 256)
                    *(reinterpret_cast<float4*>(wbuf) + e) =
                        *(reinterpret_cast<const float4*>(Wc2 + kc * 8192) + e);
                __syncthreads();
                #pragma unroll 4
                for (int k = 0; k < 64; ++k) {
                    float a = rr[ln][kc * 64 + k];
                    float4 w0 = *reinterpret_cast<const float4*>(&wbuf[k * 128 + c0]);
                    float4 w1 = *reinterpret_cast<const float4*>(&wbuf[k * 128 + 64 + c0]);
                    P0[0] += a * w0.x; P0[1] += a * w0.y; P0[2] += a * w0.z; P0[3] += a * w0.w;
                    P1[0] += a * w1.x; P1[1] += a * w1.y; P1[2] += a * w1.z; P1[3] += a * w1.w;
                }
            }
            float4 op = {P0[0], P0[1], P0[2], P0[3]};
            *reinterpret_cast<float4*>(pl + (long)n * FEAT + c0) = op;
            float4 bv = *reinterpret_cast<const float4*>(bl2 + c0);
            float4 oq = {P1[0] + bv.x + xsl[ln][c0 + 0],
                         P1[1] + bv.y + xsl[ln][c0 + 1],
                         P1[2] + bv.z + xsl[ln][c0 + 2],
                         P1[3] + bv.w + xsl[ln][c0 + 3]};
            *reinterpret_cast<float4*>(q + (long)n * FEAT + c0) = oq;
        }
        gsync(bar);
        // ===== epi phase (R7 body): hnext = h + dt * clip(q + mean(pl_nbr)) =====
        {
            const int m = cnt[n];
            const int* l = lists + (long)n * CAP;
            const float inv = 1.0f / degf[n];
            float4 a = {0, 0, 0, 0};
            for (int e = 0; e < m; ++e) {
                float4 b = *reinterpret_cast<const float4*>(pl + (long)l[e] * FEAT + c0);
                a.x += b.x; a.y += b.y; a.z += b.z; a.w += b.w;
            }
            const float dt = tspan[s + 1] - tspan[s];
            float4 qv = *reinterpret_cast<const float4*>(q + (long)n * FEAT + c0);
            float4 hv = *reinterpret_cast<const float4*>(h + (long)n * FEAT + c0);
            float s0 = qv.x + a.x * inv, s1 = qv.y + a.y * inv;
            float s2 = qv.z + a.z * inv, s3 = qv.w + a.w * inv;
            s0 = fminf(fmaxf(s0, -1000.f), 1000.f); s1 = fminf(fmaxf(s1, -1000.f), 1000.f);
            s2 = fminf(fmaxf(s2, -1000.f), 1000.f); s3 = fminf(fmaxf(s3, -1000.f), 1000.f);
            float4 o = {hv.x + dt * s0, hv.y + dt * s1, hv.z + dt * s2, hv.w + dt * s3};
            *reinterpret_cast<float4*>(hnext + (long)n * FEAT + c0) = o;
        }
        if (s < 2) gsync(bar);
    }
}

extern "C" void kernel_launch(void* const* d_in, const int* in_sizes, int n_in,
                              void* d_out, int out_size, void* d_ws, size_t ws_size,
                              hipStream_t stream) {
    const float* tspan = (const float*)d_in[0];
    const float* x     = (const float*)d_in[1];
    const float* adj   = (const float*)d_in[2];
    const float* We1   = (const float*)d_in[3];
    const float* be1   = (const float*)d_in[4];
    const float* We2   = (const float*)d_in[5];
    const float* be2   = (const float*)d_in[6];
    const float* Wf1   = (const float*)d_in[7];
    const float* bf1   = (const float*)d_in[8];
    const float* Wf2   = (const float*)d_in[9];
    const float* bf2   = (const float*)d_in[10];
    const float* Wl1   = (const float*)d_in[11];
    const float* bl1   = (const float*)d_in[12];
    const float* Wr1   = (const float*)d_in[13];
    const float* Wl2   = (const float*)d_in[14];
    const float* bl2   = (const float*)d_in[15];
    const float* Wr2   = (const float*)d_in[16];
    float* out = (float*)d_out;

    // workspace layout (bytes)
    char* ws = (char*)d_ws;
    int*      lists = (int*)     (ws + 0);           // 8000*64*4  = 2,048,000
    int*      cnt   = (int*)     (ws + 2048000);     // 32,000
    float*    degf  = (float*)   (ws + 2080000);     // 32,000
    float*    Ws1   = (float*)   (ws + 2112000);     // 65,536
    float*    Wc2   = (float*)   (ws + 2177536);     // 65,536
    float*    pl    = (float*)   (ws + 2243072);     // 2,048,000
    float*    q     = (float*)   (ws + 4291072);     // 2,048,000
    unsigned* bar   = (unsigned*)(ws + 6339072);     // 128
    // total 6,339,200 bytes

    zero_kernel<<<32, 256, 0, stream>>>(cnt, bar);
    build_adj_kernel<<<62500, 256, 0, stream>>>(adj, cnt, lists);
    mega_kernel<<<NBLK, 256, 0, stream>>>(tspan, x, We1, be1, We2, be2,
                                          Wf1, bf1, Wf2, bf2,
                                          Wl1, bl1, Wr1, Wl2, bl2, Wr2,
                                          cnt, lists, degf, Ws1, Wc2,
                                          pl, q, out, bar);
}

// Round 11
// 328.254 us; speedup vs baseline: 2.7938x; 2.7938x over previous
//
#include <hip/hip_runtime.h>

#define N_NODES 8000
#define FEAT 64
#define HID 128
#define LOOKBACK 12
#define CAP 64

// ---------------- zero the per-node counters ----------------
__global__ __launch_bounds__(256)
void zero_cnt_kernel(int* __restrict__ cnt) {
    int g = blockIdx.x * 256 + threadIdx.x;
    if (g < N_NODES) cnt[g] = 0;
}

// ---------------- adjacency scan (blocks < 62500) + init encoder (blocks >= 62500) ----
// Independent work merged into one dispatch; init blocks are scheduled last and
// overlap the scan's tail.
__global__ __launch_bounds__(256)
void build_init_kernel(const float* __restrict__ adj, int* __restrict__ cnt,
                       int* __restrict__ lists,
                       const float* __restrict__ x,
                       const float* __restrict__ We1, const float* __restrict__ be1,
                       const float* __restrict__ We2, const float* __restrict__ be2,
                       float* __restrict__ out0) {
    __shared__ float sW1T[HID * LOOKBACK];   // [h][l]
    __shared__ float sB1[HID];
    __shared__ float sW2[HID];
    if (blockIdx.x < 62500) {
        long q = (long)blockIdx.x * 256 + threadIdx.x;       // float4 index
        int i  = (int)(q / (N_NODES / 4));
        int j0 = (int)(q % (N_NODES / 4)) * 4;
        float4 w = *reinterpret_cast<const float4*>(adj + (long)i * N_NODES + j0);
        float wv[4] = {w.x, w.y, w.z, w.w};
        #pragma unroll
        for (int c = 0; c < 4; ++c) {
            if (wv[c] != 0.0f) {
                int j = j0 + c;
                int p = atomicAdd(&cnt[j], 1);
                if (p < CAP) lists[(long)j * CAP + p] = i;   // edge i -> j
            }
        }
    } else {
        const int tid = threadIdx.x;
        for (int e = tid; e < HID * LOOKBACK; e += 256) {
            int l = e / HID, h = e % HID;
            sW1T[h * LOOKBACK + l] = We1[e];
        }
        for (int e = tid; e < HID; e += 256) { sB1[e] = be1[e]; sW2[e] = We2[e]; }
        __syncthreads();
        int g = ((blockIdx.x - 62500) * 256 + tid) * 4;      // 500*256*4 == N*F
        float xv[4][LOOKBACK];
        #pragma unroll
        for (int l = 0; l < LOOKBACK; ++l) {
            float4 v = *reinterpret_cast<const float4*>(x + (long)l * N_NODES * FEAT + g);
            xv[0][l] = v.x; xv[1][l] = v.y; xv[2][l] = v.z; xv[3][l] = v.w;
        }
        float b2 = be2[0];
        float acc[4] = {b2, b2, b2, b2};
        for (int h = 0; h < HID; ++h) {
            float s0 = sB1[h], s1 = s0, s2 = s0, s3 = s0;
            #pragma unroll
            for (int l = 0; l < LOOKBACK; ++l) {
                float w = sW1T[h * LOOKBACK + l];
                s0 += xv[0][l] * w; s1 += xv[1][l] * w;
                s2 += xv[2][l] * w; s3 += xv[3][l] * w;
            }
            float w2 = sW2[h];
            acc[0] += fmaxf(s0, 0.0f) * w2; acc[1] += fmaxf(s1, 0.0f) * w2;
            acc[2] += fmaxf(s2, 0.0f) * w2; acc[3] += fmaxf(s3, 0.0f) * w2;
        }
        float4 o = {acc[0], acc[1], acc[2], acc[3]};
        *reinterpret_cast<float4*>(out0 + g) = o;
    }
}

// ---------------- canonicalize: wave-bitonic sort per node + deg + weights ----
__global__ __launch_bounds__(256)
void prep_kernel(int* __restrict__ cnt, int* __restrict__ lists,
                 float* __restrict__ degf,
                 const float* __restrict__ Wl1, const float* __restrict__ Wr1,
                 const float* __restrict__ Wl2, const float* __restrict__ Wr2,
                 float* __restrict__ Ws1, float* __restrict__ Wc2) {
    if (blockIdx.x < 2000) {
        const int wv   = threadIdx.x >> 6;
        const int lane = threadIdx.x & 63;
        const int n = blockIdx.x * 4 + wv;
        int m = cnt[n];
        if (m > CAP) m = CAP;
        int v = (lane < m) ? lists[(long)n * CAP + lane] : 0x7FFFFFFF;
        #pragma unroll
        for (int k = 2; k <= 64; k <<= 1) {
            #pragma unroll
            for (int j = k >> 1; j > 0; j >>= 1) {
                int other = __shfl_xor(v, j);
                bool keepMin = (((lane & j) == 0) == ((lane & k) == 0));
                int mn = v < other ? v : other;
                int mx = v < other ? other : v;
                v = keepMin ? mn : mx;
            }
        }
        lists[(long)n * CAP + lane] = v;
        if (lane == 0) {
            cnt[n]  = m;
            degf[n] = (float)(m > 0 ? m : 1);
        }
    } else {
        int u = (blockIdx.x - 2000) * 256 + threadIdx.x;
        if (u < 128 * 128) {            // Ws1[k][j] = [Wl1;Wr1] row-stacked
            int k = u >> 7, j = u & 127;
            Ws1[u] = (k < 64) ? Wl1[k * 128 + j] : Wr1[(k - 64) * 128 + j];
        } else if (u < 2 * 128 * 128) { // Wc2[k][j] = [Wl2 | Wr2] col-stacked
            int w = u - 128 * 128;
            int k = w >> 7, j = w & 127;
            Wc2[w] = (j < 64) ? Wl2[k * 64 + j] : Wr2[k * 64 + (j - 64)];
        }
    }
}

// ---------------- fused SAGE1 + proj + selfMLP: 4x4 register tile ----------------
// 16 nodes/block, 500 blocks (2 blocks/CU). Activations transposed in LDS
// (vT[k][node], stride 20 -> banks spread). GEMM phases: 128 threads, each owns
// 4 cols x 4 nodes -> per k: 16B weights + 16B acts = 32B LDS for 16 FMA.
// Weight panels staged to wbuf (32 KB) by all 256 threads, as in R7.
// k-iteration order identical to R7 -> bit-identical output.
__global__ __launch_bounds__(256)
void sageproj_kernel(const float* __restrict__ h, const int* __restrict__ lists,
                     const int* __restrict__ cnt, const float* __restrict__ degf,
                     const float* __restrict__ Ws1, const float* __restrict__ bl1,
                     const float* __restrict__ Wc2, const float* __restrict__ bl2,
                     const float* __restrict__ Wf1, const float* __restrict__ bf1,
                     const float* __restrict__ Wf2, const float* __restrict__ bf2,
                     float* __restrict__ pl, float* __restrict__ q) {
    __shared__ float vT[128][20];    // [k][node]: k<64 aggr, k>=64 h row
    __shared__ float rrT[128][20];   // r1 transposed
    __shared__ float ttT[128][20];   // t transposed
    __shared__ float xslT[64][20];   // xs transposed
    __shared__ float wbuf[64 * 128]; // 32 KB weight panel chunk
    const int tid = threadIdx.x;
    const int nb = blockIdx.x * 16;
    {   // gather: 16 threads/node, 4 feats each; write transposed
        const int ln = tid >> 4, sub = tid & 15;
        const int n = nb + ln;
        const int f0 = sub * 4;
        const int m = cnt[n];
        const int* l = lists + (long)n * CAP;
        const float inv = 1.0f / degf[n];
        float4 a = {0, 0, 0, 0};
        for (int e = 0; e < m; ++e) {
            float4 b = *reinterpret_cast<const float4*>(h + (long)l[e] * FEAT + f0);
            a.x += b.x; a.y += b.y; a.z += b.z; a.w += b.w;
        }
        vT[f0 + 0][ln] = a.x * inv; vT[f0 + 1][ln] = a.y * inv;
        vT[f0 + 2][ln] = a.z * inv; vT[f0 + 3][ln] = a.w * inv;
        float4 hv = *reinterpret_cast<const float4*>(h + (long)n * FEAT + f0);
        vT[64 + f0 + 0][ln] = hv.x; vT[64 + f0 + 1][ln] = hv.y;
        vT[64 + f0 + 2][ln] = hv.z; vT[64 + f0 + 3][ln] = hv.w;
    }
    const int cg = tid & 31, ng = (tid >> 5) & 3;   // GEMM map (tid < 128)
    const int c0 = cg * 4, n0 = ng * 4;
    // ---- P1: rrT = relu([aggr|h]^T @ Ws1 + bl1), K=128 in 2 staged chunks ----
    {
        float acc[4][4];
        if (tid < 128) {
            #pragma unroll
            for (int c = 0; c < 4; ++c) {
                float b = bl1[c0 + c];
                #pragma unroll
                for (int n = 0; n < 4; ++n) acc[c][n] = b;
            }
        }
        for (int kc = 0; kc < 2; ++kc) {
            __syncthreads();                 // vT ready / prev wbuf consumers done
            for (int e = tid; e < 2048; e += 256)
                *(reinterpret_cast<float4*>(wbuf) + e) =
                    *(reinterpret_cast<const float4*>(Ws1 + kc * 8192) + e);
            __syncthreads();
            if (tid < 128) {
                #pragma unroll 4
                for (int k = 0; k < 64; ++k) {
                    float4 w = *reinterpret_cast<const float4*>(&wbuf[k * 128 + c0]);
                    float4 a = *reinterpret_cast<const float4*>(&vT[kc * 64 + k][n0]);
                    float wv[4] = {w.x, w.y, w.z, w.w};
                    float av[4] = {a.x, a.y, a.z, a.w};
                    #pragma unroll
                    for (int c = 0; c < 4; ++c)
                        #pragma unroll
                        for (int n = 0; n < 4; ++n) acc[c][n] += av[n] * wv[c];
                }
            }
        }
        if (tid < 128) {
            #pragma unroll
            for (int c = 0; c < 4; ++c) {
                float4 o = {fmaxf(acc[c][0],0.f), fmaxf(acc[c][1],0.f),
                            fmaxf(acc[c][2],0.f), fmaxf(acc[c][3],0.f)};
                *reinterpret_cast<float4*>(&rrT[c0 + c][n0]) = o;
            }
        }
    }
    // ---- P2: ttT = relu(h^T @ Wf1 + bf1), K=64, one chunk ----
    {
        float acc[4][4];
        if (tid < 128) {
            #pragma unroll
            for (int c = 0; c < 4; ++c) {
                float b = bf1[c0 + c];
                #pragma unroll
                for (int n = 0; n < 4; ++n) acc[c][n] = b;
            }
        }
        __syncthreads();
        for (int e = tid; e < 2048; e += 256)
            *(reinterpret_cast<float4*>(wbuf) + e) =
                *(reinterpret_cast<const float4*>(Wf1) + e);
        __syncthreads();
        if (tid < 128) {
            #pragma unroll 4
            for (int k = 0; k < 64; ++k) {
                float4 w = *reinterpret_cast<const float4*>(&wbuf[k * 128 + c0]);
                float4 a = *reinterpret_cast<const float4*>(&vT[64 + k][n0]);
                float wv[4] = {w.x, w.y, w.z, w.w};
                float av[4] = {a.x, a.y, a.z, a.w};
                #pragma unroll
                for (int c = 0; c < 4; ++c)
                    #pragma unroll
                    for (int n = 0; n < 4; ++n) acc[c][n] += av[n] * wv[c];
            }
            #pragma unroll
            for (int c = 0; c < 4; ++c) {
                float4 o = {fmaxf(acc[c][0],0.f), fmaxf(acc[c][1],0.f),
                            fmaxf(acc[c][2],0.f), fmaxf(acc[c][3],0.f)};
                *reinterpret_cast<float4*>(&ttT[c0 + c][n0]) = o;
            }
        }
    }
    // ---- P3: xslT = ttT^T @ Wf2 + bf2, 64 cols, K=128, one chunk ----
    {
        const int cg3 = tid & 15, ng3 = (tid >> 4) & 3;
        const int c3 = cg3 * 4, n3 = ng3 * 4;
        float acc[4][4];
        if (tid < 64) {
            #pragma unroll
            for (int c = 0; c < 4; ++c) {
                float b = bf2[c3 + c];
                #pragma unroll
                for (int n = 0; n < 4; ++n) acc[c][n] = b;
            }
        }
        __syncthreads();                     // ttT ready / wbuf consumers done
        for (int e = tid; e < 2048; e += 256)
            *(reinterpret_cast<float4*>(wbuf) + e) =
                *(reinterpret_cast<const float4*>(Wf2) + e);
        __syncthreads();
        if (tid < 64) {
            #pragma unroll 4
            for (int k = 0; k < 128; ++k) {
                float4 w = *reinterpret_cast<const float4*>(&wbuf[k * 64 + c3]);
                float4 a = *reinterpret_cast<const float4*>(&ttT[k][n3]);
                float wv[4] = {w.x, w.y, w.z, w.w};
                float av[4] = {a.x, a.y, a.z, a.w};
                #pragma unroll
                for (int c = 0; c < 4; ++c)
                    #pragma unroll
                    for (int n = 0; n < 4; ++n) acc[c][n] += av[n] * wv[c];
            }
            #pragma unroll
            for (int c = 0; c < 4; ++c) {
                float4 o = {acc[c][0], acc[c][1], acc[c][2], acc[c][3]};
                *reinterpret_cast<float4*>(&xslT[c3 + c][n3]) = o;
            }
        }
    }
    // ---- P4: P = rrT^T @ Wc2; cols<64 -> pl, cols>=64 -> q (+bl2+xsl), K=128 ----
    {
        float acc[4][4];
        if (tid < 128) {
            #pragma unroll
            for (int c = 0; c < 4; ++c)
                #pragma unroll
                for (int n = 0; n < 4; ++n) acc[c][n] = 0.0f;
        }
        for (int kc = 0; kc < 2; ++kc) {
            __syncthreads();                 // xslT ready / wbuf consumers done
            for (int e = tid; e < 2048; e += 256)
                *(reinterpret_cast<float4*>(wbuf) + e) =
                    *(reinterpret_cast<const float4*>(Wc2 + kc * 8192) + e);
            __syncthreads();
            if (tid < 128) {
                #pragma unroll 4
                for (int k = 0; k < 64; ++k) {
                    float4 w = *reinterpret_cast<const float4*>(&wbuf[k * 128 + c0]);
                    float4 a = *reinterpret_cast<const float4*>(&rrT[kc * 64 + k][n0]);
                    float wv[4] = {w.x, w.y, w.z, w.w};
                    float av[4] = {a.x, a.y, a.z, a.w};
                    #pragma unroll
                    for (int c = 0; c < 4; ++c)
                        #pragma unroll
                        for (int n = 0; n < 4; ++n) acc[c][n] += av[n] * wv[c];
                }
            }
        }
        if (tid < 128) {
            if (cg < 16) {                   // pl cols c0..c0+3
                #pragma unroll
                for (int n = 0; n < 4; ++n) {
                    float4 o = {acc[0][n], acc[1][n], acc[2][n], acc[3][n]};
                    *reinterpret_cast<float4*>(pl + (long)(nb + n0 + n) * FEAT + c0) = o;
                }
            } else {                         // q cols cq..cq+3
                const int cq = c0 - 64;
                #pragma unroll
                for (int n = 0; n < 4; ++n) {
                    float4 o = {acc[0][n] + bl2[cq + 0] + xslT[cq + 0][n0 + n],
                                acc[1][n] + bl2[cq + 1] + xslT[cq + 1][n0 + n],
                                acc[2][n] + bl2[cq + 2] + xslT[cq + 2][n0 + n],
                                acc[3][n] + bl2[cq + 3] + xslT[cq + 3][n0 + n]};
                    *reinterpret_cast<float4*>(q + (long)(nb + n0 + n) * FEAT + cq) = o;
                }
            }
        }
    }
}

// ---------------- gather + Euler epilogue ----------------
__global__ __launch_bounds__(256)
void epi_kernel(const float* __restrict__ pl, const float* __restrict__ q,
                const int* __restrict__ lists, const int* __restrict__ cnt,
                const float* __restrict__ degf, const float* __restrict__ hcur,
                const float* __restrict__ tspan, int step,
                float* __restrict__ hnext) {
    const int tid = threadIdx.x;
    const int ln = tid >> 4, sub = tid & 15;
    const int n = blockIdx.x * 16 + ln;
    const int f0 = sub * 4;
    const int m = cnt[n];
    const int* l = lists + (long)n * CAP;
    const float inv = 1.0f / degf[n];
    float4 a = {0, 0, 0, 0};
    for (int e = 0; e < m; ++e) {
        float4 b = *reinterpret_cast<const float4*>(pl + (long)l[e] * FEAT + f0);
        a.x += b.x; a.y += b.y; a.z += b.z; a.w += b.w;
    }
    const float dt = tspan[step + 1] - tspan[step];
    float4 qv = *reinterpret_cast<const float4*>(q + (long)n * FEAT + f0);
    float4 hv = *reinterpret_cast<const float4*>(hcur + (long)n * FEAT + f0);
    float s0 = qv.x + a.x * inv, s1 = qv.y + a.y * inv;
    float s2 = qv.z + a.z * inv, s3 = qv.w + a.w * inv;
    s0 = fminf(fmaxf(s0, -1000.f), 1000.f); s1 = fminf(fmaxf(s1, -1000.f), 1000.f);
    s2 = fminf(fmaxf(s2, -1000.f), 1000.f); s3 = fminf(fmaxf(s3, -1000.f), 1000.f);
    float4 o = {hv.x + dt * s0, hv.y + dt * s1, hv.z + dt * s2, hv.w + dt * s3};
    *reinterpret_cast<float4*>(hnext + (long)n * FEAT + f0) = o;
}

extern "C" void kernel_launch(void* const* d_in, const int* in_sizes, int n_in,
                              void* d_out, int out_size, void* d_ws, size_t ws_size,
                              hipStream_t stream) {
    const float* tspan = (const float*)d_in[0];
    const float* x     = (const float*)d_in[1];
    const float* adj   = (const float*)d_in[2];
    const float* We1   = (const float*)d_in[3];
    const float* be1   = (const float*)d_in[4];
    const float* We2   = (const float*)d_in[5];
    const float* be2   = (const float*)d_in[6];
    const float* Wf1   = (const float*)d_in[7];
    const float* bf1   = (const float*)d_in[8];
    const float* Wf2   = (const float*)d_in[9];
    const float* bf2   = (const float*)d_in[10];
    const float* Wl1   = (const float*)d_in[11];
    const float* bl1   = (const float*)d_in[12];
    const float* Wr1   = (const float*)d_in[13];
    const float* Wl2   = (const float*)d_in[14];
    const float* bl2   = (const float*)d_in[15];
    const float* Wr2   = (const float*)d_in[16];
    float* out = (float*)d_out;

    // workspace layout (bytes)
    char* ws = (char*)d_ws;
    int*   lists = (int*)  (ws + 0);           // 8000*64*4  = 2,048,000
    int*   cnt   = (int*)  (ws + 2048000);     // 32,000
    float* degf  = (float*)(ws + 2080000);     // 32,000
    float* Ws1   = (float*)(ws + 2112000);     // 65,536
    float* Wc2   = (float*)(ws + 2177536);     // 65,536
    float* pl    = (float*)(ws + 2243072);     // 2,048,000
    float* q     = (float*)(ws + 4291072);     // 2,048,000
    // total 6,339,072 bytes

    zero_cnt_kernel<<<32, 256, 0, stream>>>(cnt);
    build_init_kernel<<<63000, 256, 0, stream>>>(adj, cnt, lists,
                                                 x, We1, be1, We2, be2, out);
    prep_kernel<<<2128, 256, 0, stream>>>(cnt, lists, degf, Wl1, Wr1, Wl2, Wr2, Ws1, Wc2);

    for (int s = 0; s < 3; ++s) {
        const float* hcur  = out + (long)s       * N_NODES * FEAT;
        float*       hnext = out + (long)(s + 1) * N_NODES * FEAT;
        sageproj_kernel<<<500, 256, 0, stream>>>(hcur, lists, cnt, degf,
                                                 Ws1, bl1, Wc2, bl2,
                                                 Wf1, bf1, Wf2, bf2, pl, q);
        epi_kernel<<<500, 256, 0, stream>>>(pl, q, lists, cnt, degf, hcur, tspan, s, hnext);
    }
}

// Round 12
// 249.372 us; speedup vs baseline: 3.6775x; 1.3163x over previous
//
#include <hip/hip_runtime.h>

#define N_NODES 8000
#define FEAT 64
#define HID 128
#define LOOKBACK 12
#define CAP 64

// ---------------- zero the per-node counters ----------------
__global__ __launch_bounds__(256)
void zero_cnt_kernel(int* __restrict__ cnt) {
    int g = blockIdx.x * 256 + threadIdx.x;
    if (g < N_NODES) cnt[g] = 0;
}

// ---------------- adjacency pattern extraction: grid-strided, full occupancy ----
// 2048 blocks x 256 threads = 8 blocks/CU, 32 waves/CU resident; each thread
// scans ~30 float4s. Latency of loads+atomics hidden by 16x more waves in
// flight than the old 62500-tiny-block version (183 us, 25% occupancy, 10% BW).
__global__ __launch_bounds__(256)
void build_adj_kernel(const float* __restrict__ adj, int* __restrict__ cnt,
                      int* __restrict__ lists) {
    const long NQ = (long)N_NODES * N_NODES / 4;       // 16,000,000 float4s
    const long STRIDE = 2048L * 256;                   // 524,288 threads
    for (long q = (long)blockIdx.x * 256 + threadIdx.x; q < NQ; q += STRIDE) {
        float4 w = *reinterpret_cast<const float4*>(adj + 4 * q);  // i*N+j0 == 4q
        if (w.x != 0.0f || w.y != 0.0f || w.z != 0.0f || w.w != 0.0f) {
            int i  = (int)(q / (N_NODES / 4));
            int j0 = (int)(q % (N_NODES / 4)) * 4;
            float wv[4] = {w.x, w.y, w.z, w.w};
            #pragma unroll
            for (int c = 0; c < 4; ++c) {
                if (wv[c] != 0.0f) {
                    int j = j0 + c;
                    int p = atomicAdd(&cnt[j], 1);
                    if (p < CAP) lists[(long)j * CAP + p] = i;     // edge i -> j
                }
            }
        }
    }
}

// ---------------- canonicalize: wave-bitonic sort per node + deg + weights ----
__global__ __launch_bounds__(256)
void prep_kernel(int* __restrict__ cnt, int* __restrict__ lists,
                 float* __restrict__ degf,
                 const float* __restrict__ Wl1, const float* __restrict__ Wr1,
                 const float* __restrict__ Wl2, const float* __restrict__ Wr2,
                 float* __restrict__ Ws1, float* __restrict__ Wc2) {
    if (blockIdx.x < 2000) {
        const int wv   = threadIdx.x >> 6;
        const int lane = threadIdx.x & 63;
        const int n = blockIdx.x * 4 + wv;
        int m = cnt[n];
        if (m > CAP) m = CAP;
        int v = (lane < m) ? lists[(long)n * CAP + lane] : 0x7FFFFFFF;
        #pragma unroll
        for (int k = 2; k <= 64; k <<= 1) {
            #pragma unroll
            for (int j = k >> 1; j > 0; j >>= 1) {
                int other = __shfl_xor(v, j);
                bool keepMin = (((lane & j) == 0) == ((lane & k) == 0));
                int mn = v < other ? v : other;
                int mx = v < other ? other : v;
                v = keepMin ? mn : mx;
            }
        }
        lists[(long)n * CAP + lane] = v;
        if (lane == 0) {
            cnt[n]  = m;
            degf[n] = (float)(m > 0 ? m : 1);
        }
    } else {
        int u = (blockIdx.x - 2000) * 256 + threadIdx.x;
        if (u < 128 * 128) {            // Ws1[k][j] = [Wl1;Wr1] row-stacked
            int k = u >> 7, j = u & 127;
            Ws1[u] = (k < 64) ? Wl1[k * 128 + j] : Wr1[(k - 64) * 128 + j];
        } else if (u < 2 * 128 * 128) { // Wc2[k][j] = [Wl2 | Wr2] col-stacked
            int w = u - 128 * 128;
            int k = w >> 7, j = w & 127;
            Wc2[w] = (j < 64) ? Wl2[k * 64 + j] : Wr2[k * 64 + (j - 64)];
        }
    }
}

// ---------------- init encoder: x[L,N,F] -> x0[N,F], 4 elems/thread ----------------
__global__ __launch_bounds__(256)
void init_enc_kernel(const float* __restrict__ x, const float* __restrict__ We1,
                     const float* __restrict__ be1, const float* __restrict__ We2,
                     const float* __restrict__ be2, float* __restrict__ out0) {
    __shared__ float sW1T[HID * LOOKBACK];   // [h][l]
    __shared__ float sB1[HID];
    __shared__ float sW2[HID];
    for (int e = threadIdx.x; e < HID * LOOKBACK; e += 256) {
        int l = e / HID, h = e % HID;
        sW1T[h * LOOKBACK + l] = We1[e];
    }
    for (int e = threadIdx.x; e < HID; e += 256) { sB1[e] = be1[e]; sW2[e] = We2[e]; }
    __syncthreads();
    int g = (blockIdx.x * 256 + threadIdx.x) * 4;
    if (g >= N_NODES * FEAT) return;
    float xv[4][LOOKBACK];
    #pragma unroll
    for (int l = 0; l < LOOKBACK; ++l) {
        float4 v = *reinterpret_cast<const float4*>(x + (long)l * N_NODES * FEAT + g);
        xv[0][l] = v.x; xv[1][l] = v.y; xv[2][l] = v.z; xv[3][l] = v.w;
    }
    float b2 = be2[0];
    float acc[4] = {b2, b2, b2, b2};
    for (int h = 0; h < HID; ++h) {
        float s0 = sB1[h], s1 = s0, s2 = s0, s3 = s0;
        #pragma unroll
        for (int l = 0; l < LOOKBACK; ++l) {
            float w = sW1T[h * LOOKBACK + l];
            s0 += xv[0][l] * w; s1 += xv[1][l] * w;
            s2 += xv[2][l] * w; s3 += xv[3][l] * w;
        }
        float w2 = sW2[h];
        acc[0] += fmaxf(s0, 0.0f) * w2; acc[1] += fmaxf(s1, 0.0f) * w2;
        acc[2] += fmaxf(s2, 0.0f) * w2; acc[3] += fmaxf(s3, 0.0f) * w2;
    }
    float4 o = {acc[0], acc[1], acc[2], acc[3]};
    *reinterpret_cast<float4*>(out0 + g) = o;
}

// ---------------- fused SAGE1 + proj + selfMLP (R7 LDS-staged weights) ----------------
// 16 nodes/block, 500 blocks (2 blocks/CU, 2 waves/SIMD).
__global__ __launch_bounds__(256)
void sageproj_kernel(const float* __restrict__ h, const int* __restrict__ lists,
                     const int* __restrict__ cnt, const float* __restrict__ degf,
                     const float* __restrict__ Ws1, const float* __restrict__ bl1,
                     const float* __restrict__ Wc2, const float* __restrict__ bl2,
                     const float* __restrict__ Wf1, const float* __restrict__ bf1,
                     const float* __restrict__ Wf2, const float* __restrict__ bf2,
                     float* __restrict__ pl, float* __restrict__ q) {
    __shared__ float v[16][132];     // [node][k]: k<64 aggr, k>=64 h row
    __shared__ float rr[16][132];    // r1
    __shared__ float tt[16][132];    // t = relu(h@Wf1+bf1)
    __shared__ float xsl[16][68];    // xs
    __shared__ float wbuf[64 * 128]; // 32 KB weight panel chunk
    const int tid = threadIdx.x;
    const int nb = blockIdx.x * 16;
    const int ln = tid >> 4, jg = tid & 15;
    const int n = nb + ln;
    const int c0 = jg * 4;
    {   // gather: 16 threads/node, 4 feats each
        const int m = cnt[n];
        const int* l = lists + (long)n * CAP;
        const float inv = 1.0f / degf[n];
        float4 a = {0, 0, 0, 0};
        for (int e = 0; e < m; ++e) {
            float4 b = *reinterpret_cast<const float4*>(h + (long)l[e] * FEAT + c0);
            a.x += b.x; a.y += b.y; a.z += b.z; a.w += b.w;
        }
        float4 av = {a.x * inv, a.y * inv, a.z * inv, a.w * inv};
        *reinterpret_cast<float4*>(&v[ln][c0]) = av;
        *reinterpret_cast<float4*>(&v[ln][64 + c0]) =
            *reinterpret_cast<const float4*>(h + (long)n * FEAT + c0);
    }
    // ---- P1: rr = relu([aggr|h] @ Ws1 + bl1), K=128 in 2 chunks ----
    {
        float4 b0 = *reinterpret_cast<const float4*>(bl1 + c0);
        float4 b1 = *reinterpret_cast<const float4*>(bl1 + 64 + c0);
        float A0[4] = {b0.x, b0.y, b0.z, b0.w};
        float A1[4] = {b1.x, b1.y, b1.z, b1.w};
        for (int kc = 0; kc < 2; ++kc) {
            __syncthreads();                     // prev consumers done / v ready
            for (int e = tid; e < 2048; e += 256)
                *(reinterpret_cast<float4*>(wbuf) + e) =
                    *(reinterpret_cast<const float4*>(Ws1 + kc * 8192) + e);
            __syncthreads();
            #pragma unroll 4
            for (int k = 0; k < 64; ++k) {
                float a = v[ln][kc * 64 + k];
                float4 w0 = *reinterpret_cast<const float4*>(&wbuf[k * 128 + c0]);
                float4 w1 = *reinterpret_cast<const float4*>(&wbuf[k * 128 + 64 + c0]);
                A0[0] += a * w0.x; A0[1] += a * w0.y; A0[2] += a * w0.z; A0[3] += a * w0.w;
                A1[0] += a * w1.x; A1[1] += a * w1.y; A1[2] += a * w1.z; A1[3] += a * w1.w;
            }
        }
        float4 o0 = {fmaxf(A0[0],0.f), fmaxf(A0[1],0.f), fmaxf(A0[2],0.f), fmaxf(A0[3],0.f)};
        float4 o1 = {fmaxf(A1[0],0.f), fmaxf(A1[1],0.f), fmaxf(A1[2],0.f), fmaxf(A1[3],0.f)};
        *reinterpret_cast<float4*>(&rr[ln][c0]) = o0;
        *reinterpret_cast<float4*>(&rr[ln][64 + c0]) = o1;
    }
    // ---- P2: tt = relu(h @ Wf1 + bf1), K=64, one chunk ----
    {
        float4 b0 = *reinterpret_cast<const float4*>(bf1 + c0);
        float4 b1 = *reinterpret_cast<const float4*>(bf1 + 64 + c0);
        float A0[4] = {b0.x, b0.y, b0.z, b0.w};
        float A1[4] = {b1.x, b1.y, b1.z, b1.w};
        __syncthreads();
        for (int e = tid; e < 2048; e += 256)
            *(reinterpret_cast<float4*>(wbuf) + e) =
                *(reinterpret_cast<const float4*>(Wf1) + e);
        __syncthreads();
        #pragma unroll 4
        for (int k = 0; k < 64; ++k) {
            float a = v[ln][64 + k];
            float4 w0 = *reinterpret_cast<const float4*>(&wbuf[k * 128 + c0]);
            float4 w1 = *reinterpret_cast<const float4*>(&wbuf[k * 128 + 64 + c0]);
            A0[0] += a * w0.x; A0[1] += a * w0.y; A0[2] += a * w0.z; A0[3] += a * w0.w;
            A1[0] += a * w1.x; A1[1] += a * w1.y; A1[2] += a * w1.z; A1[3] += a * w1.w;
        }
        float4 o0 = {fmaxf(A0[0],0.f), fmaxf(A0[1],0.f), fmaxf(A0[2],0.f), fmaxf(A0[3],0.f)};
        float4 o1 = {fmaxf(A1[0],0.f), fmaxf(A1[1],0.f), fmaxf(A1[2],0.f), fmaxf(A1[3],0.f)};
        *reinterpret_cast<float4*>(&tt[ln][c0]) = o0;
        *reinterpret_cast<float4*>(&tt[ln][64 + c0]) = o1;
    }
    // ---- P3: xsl = tt @ Wf2 + bf2, K=128, 64 cols, one chunk (Wf2 = [128][64]) ----
    {
        float4 b0 = *reinterpret_cast<const float4*>(bf2 + c0);
        float X[4] = {b0.x, b0.y, b0.z, b0.w};
        __syncthreads();
        for (int e = tid; e < 2048; e += 256)
            *(reinterpret_cast<float4*>(wbuf) + e) =
                *(reinterpret_cast<const float4*>(Wf2) + e);
        __syncthreads();
        #pragma unroll 4
        for (int k = 0; k < 128; ++k) {
            float a = tt[ln][k];
            float4 w = *reinterpret_cast<const float4*>(&wbuf[k * 64 + c0]);
            X[0] += a * w.x; X[1] += a * w.y; X[2] += a * w.z; X[3] += a * w.w;
        }
        float4 o = {X[0], X[1], X[2], X[3]};
        *reinterpret_cast<float4*>(&xsl[ln][c0]) = o;
    }
    // ---- P4: [pl|q] = rr @ Wc2 (+ bl2 + xsl on q half), K=128 in 2 chunks ----
    {
        float P0[4] = {0, 0, 0, 0};
        float P1[4] = {0, 0, 0, 0};
        for (int kc = 0; kc < 2; ++kc) {
            __syncthreads();
            for (int e = tid; e < 2048; e += 256)
                *(reinterpret_cast<float4*>(wbuf) + e) =
                    *(reinterpret_cast<const float4*>(Wc2 + kc * 8192) + e);
            __syncthreads();
            #pragma unroll 4
            for (int k = 0; k < 64; ++k) {
                float a = rr[ln][kc * 64 + k];
                float4 w0 = *reinterpret_cast<const float4*>(&wbuf[k * 128 + c0]);
                float4 w1 = *reinterpret_cast<const float4*>(&wbuf[k * 128 + 64 + c0]);
                P0[0] += a * w0.x; P0[1] += a * w0.y; P0[2] += a * w0.z; P0[3] += a * w0.w;
                P1[0] += a * w1.x; P1[1] += a * w1.y; P1[2] += a * w1.z; P1[3] += a * w1.w;
            }
        }
        float4 op = {P0[0], P0[1], P0[2], P0[3]};
        *reinterpret_cast<float4*>(pl + (long)n * FEAT + c0) = op;
        float4 bv = *reinterpret_cast<const float4*>(bl2 + c0);
        float4 oq = {P1[0] + bv.x + xsl[ln][c0 + 0],
                     P1[1] + bv.y + xsl[ln][c0 + 1],
                     P1[2] + bv.z + xsl[ln][c0 + 2],
                     P1[3] + bv.w + xsl[ln][c0 + 3]};
        *reinterpret_cast<float4*>(q + (long)n * FEAT + c0) = oq;
    }
}

// ---------------- gather + Euler epilogue ----------------
__global__ __launch_bounds__(256)
void epi_kernel(const float* __restrict__ pl, const float* __restrict__ q,
                const int* __restrict__ lists, const int* __restrict__ cnt,
                const float* __restrict__ degf, const float* __restrict__ hcur,
                const float* __restrict__ tspan, int step,
                float* __restrict__ hnext) {
    const int tid = threadIdx.x;
    const int ln = tid >> 4, sub = tid & 15;
    const int n = blockIdx.x * 16 + ln;
    const int f0 = sub * 4;
    const int m = cnt[n];
    const int* l = lists + (long)n * CAP;
    const float inv = 1.0f / degf[n];
    float4 a = {0, 0, 0, 0};
    for (int e = 0; e < m; ++e) {
        float4 b = *reinterpret_cast<const float4*>(pl + (long)l[e] * FEAT + f0);
        a.x += b.x; a.y += b.y; a.z += b.z; a.w += b.w;
    }
    const float dt = tspan[step + 1] - tspan[step];
    float4 qv = *reinterpret_cast<const float4*>(q + (long)n * FEAT + f0);
    float4 hv = *reinterpret_cast<const float4*>(hcur + (long)n * FEAT + f0);
    float s0 = qv.x + a.x * inv, s1 = qv.y + a.y * inv;
    float s2 = qv.z + a.z * inv, s3 = qv.w + a.w * inv;
    s0 = fminf(fmaxf(s0, -1000.f), 1000.f); s1 = fminf(fmaxf(s1, -1000.f), 1000.f);
    s2 = fminf(fmaxf(s2, -1000.f), 1000.f); s3 = fminf(fmaxf(s3, -1000.f), 1000.f);
    float4 o = {hv.x + dt * s0, hv.y + dt * s1, hv.z + dt * s2, hv.w + dt * s3};
    *reinterpret_cast<float4*>(hnext + (long)n * FEAT + f0) = o;
}

extern "C" void kernel_launch(void* const* d_in, const int* in_sizes, int n_in,
                              void* d_out, int out_size, void* d_ws, size_t ws_size,
                              hipStream_t stream) {
    const float* tspan = (const float*)d_in[0];
    const float* x     = (const float*)d_in[1];
    const float* adj   = (const float*)d_in[2];
    const float* We1   = (const float*)d_in[3];
    const float* be1   = (const float*)d_in[4];
    const float* We2   = (const float*)d_in[5];
    const float* be2   = (const float*)d_in[6];
    const float* Wf1   = (const float*)d_in[7];
    const float* bf1   = (const float*)d_in[8];
    const float* Wf2   = (const float*)d_in[9];
    const float* bf2   = (const float*)d_in[10];
    const float* Wl1   = (const float*)d_in[11];
    const float* bl1   = (const float*)d_in[12];
    const float* Wr1   = (const float*)d_in[13];
    const float* Wl2   = (const float*)d_in[14];
    const float* bl2   = (const float*)d_in[15];
    const float* Wr2   = (const float*)d_in[16];
    float* out = (float*)d_out;

    // workspace layout (bytes)
    char* ws = (char*)d_ws;
    int*   lists = (int*)  (ws + 0);           // 8000*64*4  = 2,048,000
    int*   cnt   = (int*)  (ws + 2048000);     // 32,000
    float* degf  = (float*)(ws + 2080000);     // 32,000
    float* Ws1   = (float*)(ws + 2112000);     // 65,536
    float* Wc2   = (float*)(ws + 2177536);     // 65,536
    float* pl    = (float*)(ws + 2243072);     // 2,048,000
    float* q     = (float*)(ws + 4291072);     // 2,048,000
    // total 6,339,072 bytes

    zero_cnt_kernel<<<32, 256, 0, stream>>>(cnt);
    build_adj_kernel<<<2048, 256, 0, stream>>>(adj, cnt, lists);
    prep_kernel<<<2128, 256, 0, stream>>>(cnt, lists, degf, Wl1, Wr1, Wl2, Wr2, Ws1, Wc2);
    init_enc_kernel<<<500, 256, 0, stream>>>(x, We1, be1, We2, be2, out);

    for (int s = 0; s < 3; ++s) {
        const float* hcur  = out + (long)s       * N_NODES * FEAT;
        float*       hnext = out + (long)(s + 1) * N_NODES * FEAT;
        sageproj_kernel<<<500, 256, 0, stream>>>(hcur, lists, cnt, degf,
                                                 Ws1, bl1, Wc2, bl2,
                                                 Wf1, bf1, Wf2, bf2, pl, q);
        epi_kernel<<<500, 256, 0, stream>>>(pl, q, lists, cnt, degf, hcur, tspan, s, hnext);
    }
}